// Round 3
// baseline (2365.127 us; speedup 1.0000x reference)
//
#include <hip/hip_runtime.h>
#include <hip/hip_bf16.h>
#include <math.h>

#define S 1024
#define D 1024
#define H 16
#define DH 64
#define L 4
#define DFF 4096

typedef unsigned short u16;
typedef __attribute__((ext_vector_type(8))) short short8;
typedef __attribute__((ext_vector_type(4))) float floatx4;
typedef __attribute__((ext_vector_type(4))) u16 ushort4v;
typedef __attribute__((ext_vector_type(8))) u16 ushort8v;

// async global->LDS, 16B per lane (m97 pattern; size must be literal)
#define GLL16(gp, lp) __builtin_amdgcn_global_load_lds( \
    (const __attribute__((address_space(1))) void*)(gp), \
    (__attribute__((address_space(3))) void*)(lp), 16, 0, 0)

// ---------------------------------------------------------------- helpers
__device__ __forceinline__ float wave_reduce_sum(float v) {
    #pragma unroll
    for (int off = 1; off < 64; off <<= 1) v += __shfl_xor(v, off, 64);
    return v;
}
__device__ __forceinline__ float wave_reduce_max(float v) {
    #pragma unroll
    for (int off = 1; off < 64; off <<= 1) v = fmaxf(v, __shfl_xor(v, off, 64));
    return v;
}
__device__ __forceinline__ float gelu_f(float x) {
    float x3 = x * x * x;
    return 0.5f * x * (1.0f + tanhf(0.7978845608028654f * (x + 0.044715f * x3)));
}
// bf16 round-to-nearest-even, raw bits
__device__ __forceinline__ u16 f2bf(float x) {
    unsigned u = __float_as_uint(x);
    return (u16)((u + 0x7FFFu + ((u >> 16) & 1u)) >> 16);
}
__device__ __forceinline__ float bf2f(u16 h) {
    return __uint_as_float(((unsigned)h) << 16);
}

// ---------------------------------------------------------------- modulation GEMVs
// mods per layer l (offset l*6*D): [0,2D) shift1|scale1 ; [2D,3D) gate1 ;
// [3D,5D) shift2|scale2 ; [5D,6D) gate2
__global__ __launch_bounds__(256) void modulation_kernel(
    const float* __restrict__ cond,
    const float* __restrict__ ada1_w, const float* __restrict__ ada1_b,
    const float* __restrict__ gate1_w, const float* __restrict__ gate1_b,
    const float* __restrict__ ada2_w, const float* __restrict__ ada2_b,
    const float* __restrict__ gate2_w, const float* __restrict__ gate2_b,
    float* __restrict__ mods)
{
    int idx = blockIdx.x * 256 + threadIdx.x;   // < L*6*D
    int l = idx / (6 * D);
    int r = idx - l * (6 * D);
    const float* w; const float* b; int col, outdim;
    if (r < 2 * D)      { w = ada1_w  + (size_t)l * D * 2 * D; b = ada1_b  + l * 2 * D; col = r;          outdim = 2 * D; }
    else if (r < 3 * D) { w = gate1_w + (size_t)l * D * D;     b = gate1_b + l * D;     col = r - 2 * D;  outdim = D; }
    else if (r < 5 * D) { w = ada2_w  + (size_t)l * D * 2 * D; b = ada2_b  + l * 2 * D; col = r - 3 * D;  outdim = 2 * D; }
    else                { w = gate2_w + (size_t)l * D * D;     b = gate2_b + l * D;     col = r - 5 * D;  outdim = D; }
    float acc = b[col];
    for (int k = 0; k < D; k++) acc += cond[k] * w[(size_t)k * outdim + col];
    mods[idx] = acc;
}

// ---------------------------------------------------------------- LayerNorm + adaLN -> bf16 hi/lo planes
__global__ __launch_bounds__(256) void ln_mod_kernel(
    const float* __restrict__ x, const float* __restrict__ ss,
    u16* __restrict__ out_hi, u16* __restrict__ out_lo)
{
    __shared__ float red[4];
    const int row = blockIdx.x, t = threadIdx.x;
    float4 v = ((const float4*)(x + (size_t)row * D))[t];

    float s = v.x + v.y + v.z + v.w;
    s = wave_reduce_sum(s);
    if ((t & 63) == 0) red[t >> 6] = s;
    __syncthreads();
    float mean = (red[0] + red[1] + red[2] + red[3]) * (1.0f / D);

    float dx = v.x - mean, dy = v.y - mean, dz = v.z - mean, dw = v.w - mean;
    float s2 = dx * dx + dy * dy + dz * dz + dw * dw;
    __syncthreads();
    s2 = wave_reduce_sum(s2);
    if ((t & 63) == 0) red[t >> 6] = s2;
    __syncthreads();
    float var = (red[0] + red[1] + red[2] + red[3]) * (1.0f / D);
    float rstd = rsqrtf(var + 1e-5f);

    int c = t * 4;
    float ov[4];
    ov[0] = dx * rstd * (1.0f + ss[D + c + 0]) + ss[c + 0];
    ov[1] = dy * rstd * (1.0f + ss[D + c + 1]) + ss[c + 1];
    ov[2] = dz * rstd * (1.0f + ss[D + c + 2]) + ss[c + 2];
    ov[3] = dw * rstd * (1.0f + ss[D + c + 3]) + ss[c + 3];
    ushort4v hv, lv;
    #pragma unroll
    for (int j = 0; j < 4; j++) {
        u16 h = f2bf(ov[j]);
        hv[j] = h;
        lv[j] = f2bf(ov[j] - bf2f(h));
    }
    *(ushort4v*)&out_hi[(size_t)row * D + c] = hv;
    *(ushort4v*)&out_lo[(size_t)row * D + c] = lv;
}

// ---------------------------------------------------------------- weight convert+transpose: W[K][N] f32 -> Wt hi/lo [N][K] bf16
__global__ __launch_bounds__(256) void convert_w_kernel(
    const float* __restrict__ W, u16* __restrict__ Wh, u16* __restrict__ Wl,
    int K, int N)
{
    __shared__ float t[64][65];
    const int n0 = blockIdx.x * 64, k0 = blockIdx.y * 64;
    const int tid = threadIdx.x;
    const int r = tid >> 4, c4 = (tid & 15) * 4;
    #pragma unroll
    for (int i = 0; i < 4; i++) {
        float4 v = *(const float4*)(W + (size_t)(k0 + r + i * 16) * N + n0 + c4);
        t[r + i * 16][c4 + 0] = v.x;
        t[r + i * 16][c4 + 1] = v.y;
        t[r + i * 16][c4 + 2] = v.z;
        t[r + i * 16][c4 + 3] = v.w;
    }
    __syncthreads();
    const int n = tid >> 2, kc = (tid & 3) * 16;
    ushort8v h0, h1, l0, l1;
    #pragma unroll
    for (int j = 0; j < 8; j++) {
        float x0 = t[kc + j][n];
        float x1 = t[kc + 8 + j][n];
        u16 a = f2bf(x0), b = f2bf(x1);
        h0[j] = a; h1[j] = b;
        l0[j] = f2bf(x0 - bf2f(a));
        l1[j] = f2bf(x1 - bf2f(b));
    }
    size_t base = (size_t)(n0 + n) * K + k0 + kc;
    *(ushort8v*)&Wh[base]     = h0;
    *(ushort8v*)&Wh[base + 8] = h1;
    *(ushort8v*)&Wl[base]     = l0;
    *(ushort8v*)&Wl[base + 8] = l1;
}

// ---------------------------------------------------------------- bf16x3 MFMA GEMM
// C[M,N] = epi(A[M,K] @ B^T, + bias); A,B as bf16 hi/lo planes; B pre-transposed [N][K].
// MODE 0: C fp32      MODE 1: gelu -> Ch/Cl bf16 planes     MODE 2: X += r*gate (fp32 RMW)
template<int BM, int BN, int MODE>
__global__ __launch_bounds__(256, 2) void mfma_gemm(
    const u16* __restrict__ Ah, const u16* __restrict__ Al,
    const u16* __restrict__ Bh, const u16* __restrict__ Bl,
    const float* __restrict__ bias,
    float* __restrict__ C, u16* __restrict__ Ch, u16* __restrict__ Cl,
    const float* __restrict__ gate, float* __restrict__ X,
    int K, int N)
{
    constexpr int SAe = BM * 32;            // elems per A plane (BK=32)
    constexpr int SBe = BN * 32;
    constexpr int SBUFE = 2 * SAe + 2 * SBe;
    constexpr int NSWEEP = SBUFE / 2048;    // 256 thr * 8 elems each
    constexpr int WM = BM / 2, WN = BN / 2; // 2x2 waves
    constexpr int FM = WM / 16, FN = WN / 16;

    __shared__ u16 shm[2 * SBUFE];

    const int tid  = threadIdx.x;
    const int lane = tid & 63;
    const int wave = tid >> 6;
    const int wm = wave >> 1, wn = wave & 1;

    // T1: XCD-aware bijective swizzle (all grids here have nwg % 8 == 0)
    const int nwg = gridDim.x * gridDim.y;
    int bid = blockIdx.y * gridDim.x + blockIdx.x;
    bid = (bid & 7) * (nwg >> 3) + (bid >> 3);
    const int bm = (bid / gridDim.x) * BM;
    const int bn = (bid % gridDim.x) * BN;

    const u16* gA0 = Ah + (size_t)bm * K;
    const u16* gA1 = Al + (size_t)bm * K;
    const u16* gB0 = Bh + (size_t)bn * K;
    const u16* gB1 = Bl + (size_t)bn * K;

    // LDS[phys] = G[inv(phys)]; reader uses fwd swz. fwd: e^=(e&0xE0)>>2
    // inverse: e^=((e&0xE0)>>2)^((e&0x80)>>4)   (verified involution-pair)
    auto stage = [&](int bufe, int kt) {
        const int k0 = kt * 32;
        #pragma unroll
        for (int s = 0; s < NSWEEP; s++) {
            const int pbase = s * 2048;
            const int oe = pbase + tid * 8;
            const u16* src; int pe;
            if (pbase < SAe)               { src = gA0; pe = oe; }
            else if (pbase < 2 * SAe)      { src = gA1; pe = oe - SAe; }
            else if (pbase < 2 * SAe + SBe){ src = gB0; pe = oe - 2 * SAe; }
            else                           { src = gB1; pe = oe - 2 * SAe - SBe; }
            const int ue = pe ^ ((pe & 0xE0) >> 2) ^ ((pe & 0x80) >> 4);
            const u16* g = src + (size_t)(ue >> 5) * K + k0 + (ue & 31);
            GLL16(g, &shm[bufe + oe]);
        }
    };

    floatx4 acc[FM][FN] = {};

    const int KT = K >> 5;
    stage(0, 0);
    __syncthreads();
    for (int kt = 0; kt < KT; kt++) {
        const int cur = (kt & 1) ? SBUFE : 0;
        if (kt + 1 < KT) stage(cur ^ SBUFE, kt + 1);

        short8 bhf[FN], blf[FN];
        #pragma unroll
        for (int ni = 0; ni < FN; ni++) {
            int row = wn * WN + ni * 16 + (lane & 15);
            int off = row * 32 + ((lane >> 4) << 3);
            off ^= (off & 0xE0) >> 2;
            bhf[ni] = *(const short8*)&shm[cur + 2 * SAe + off];
            blf[ni] = *(const short8*)&shm[cur + 2 * SAe + SBe + off];
        }
        #pragma unroll
        for (int mi = 0; mi < FM; mi++) {
            int row = wm * WM + mi * 16 + (lane & 15);
            int off = row * 32 + ((lane >> 4) << 3);
            off ^= (off & 0xE0) >> 2;
            short8 ahf = *(const short8*)&shm[cur + off];
            short8 alf = *(const short8*)&shm[cur + SAe + off];
            #pragma unroll
            for (int ni = 0; ni < FN; ni++) {
                acc[mi][ni] = __builtin_amdgcn_mfma_f32_16x16x32_bf16(ahf, bhf[ni], acc[mi][ni], 0, 0, 0);
                acc[mi][ni] = __builtin_amdgcn_mfma_f32_16x16x32_bf16(ahf, blf[ni], acc[mi][ni], 0, 0, 0);
                acc[mi][ni] = __builtin_amdgcn_mfma_f32_16x16x32_bf16(alf, bhf[ni], acc[mi][ni], 0, 0, 0);
            }
        }
        __syncthreads();
    }

    // epilogue: C/D frag col=lane&15, row=(lane>>4)*4+reg (m89/m91-verified)
    const int cr = (lane >> 4) << 2;
    const int cc = lane & 15;
    #pragma unroll
    for (int mi = 0; mi < FM; mi++) {
        #pragma unroll
        for (int ni = 0; ni < FN; ni++) {
            const int gcol = bn + wn * WN + ni * 16 + cc;
            const float bv = bias[gcol];
            #pragma unroll
            for (int r = 0; r < 4; r++) {
                const int grow = bm + wm * WM + mi * 16 + cr + r;
                float v = acc[mi][ni][r] + bv;
                if (MODE == 0) {
                    C[(size_t)grow * N + gcol] = v;
                } else if (MODE == 1) {
                    v = gelu_f(v);
                    u16 h = f2bf(v);
                    Ch[(size_t)grow * N + gcol] = h;
                    Cl[(size_t)grow * N + gcol] = f2bf(v - bf2f(h));
                } else {
                    X[(size_t)grow * N + gcol] += v * gate[gcol];
                }
            }
        }
    }
}

// ---------------------------------------------------------------- q/k RMSNorm + RoPE (in place, fp32 qkv)
__global__ __launch_bounds__(64) void qk_prep_kernel(float* __restrict__ qkv)
{
    const int s = blockIdx.x >> 4;
    const int h = blockIdx.x & 15;
    const int d = threadIdx.x;

    const int j = d & 31;
    float ang = (float)s * powf(10000.0f, -(float)j / 32.0f);
    float sn, cs;
    sincosf(ang, &sn, &cs);

    #pragma unroll
    for (int which = 0; which < 2; which++) {
        float* p = qkv + (size_t)s * (3 * D) + which * D + h * DH;
        float v = p[d];
        float ssum = wave_reduce_sum(v * v);
        float rms = rsqrtf(ssum * (1.0f / DH) + 1e-6f);
        float vn = v * rms;
        float other = __shfl_xor(vn, 32, 64);
        float out = (d < 32) ? (vn * cs - other * sn) : (other * sn + vn * cs);
        p[d] = out;
    }
}

// ---------------------------------------------------------------- flash attention (fp32) -> o hi/lo bf16 planes
__global__ __launch_bounds__(256) void attn_kernel(
    const float* __restrict__ qkv, u16* __restrict__ o_hi, u16* __restrict__ o_lo, int window)
{
    __shared__ float qs[64][64];
    __shared__ float ks[64][65];
    __shared__ float vs[64][64];

    const int h  = blockIdx.x;
    const int qt = blockIdx.y;
    const int t  = threadIdx.x;
    const int tx = t & 63;
    const int ty = t >> 6;
    const int qbase = qt * 64;

    #pragma unroll
    for (int l = 0; l < 16; l++) {
        int r = ty * 16 + l;
        qs[r][tx] = qkv[(size_t)(qbase + r) * (3 * D) + h * DH + tx];
    }

    float m_r[16], l_r[16], acc[16];
    #pragma unroll
    for (int jj = 0; jj < 16; jj++) { m_r[jj] = -INFINITY; l_r[jj] = 0.0f; acc[jj] = 0.0f; }

    int kt0 = qbase - (window - 1) * 8;
    kt0 = (kt0 < 0) ? 0 : (kt0 >> 6);

    for (int kt = kt0; kt <= qt; kt++) {
        const int kbase = kt * 64;
        __syncthreads();
        #pragma unroll
        for (int l = 0; l < 16; l++) {
            int r = ty * 16 + l;
            ks[r][tx] = qkv[(size_t)(kbase + r) * (3 * D) + D     + h * DH + tx];
            vs[r][tx] = qkv[(size_t)(kbase + r) * (3 * D) + 2 * D + h * DH + tx];
        }
        __syncthreads();

        const int fk = (kbase + tx) >> 3;
        #pragma unroll 1
        for (int jj = 0; jj < 16; jj++) {
            const int r = 4 * jj + ty;   // wave ty owns rows ty, ty+4, ...
            float sc = 0.0f;
            #pragma unroll
            for (int dd = 0; dd < 64; dd++) sc += qs[r][dd] * ks[tx][dd];
            const int fq = (qbase + r) >> 3;
            bool ok = (fk <= fq) && ((fq - fk) < window);
            float val = ok ? sc * 0.125f : -1e30f;

            float mx = wave_reduce_max(val);
            float mnew = fmaxf(m_r[jj], mx);
            float p = expf(val - mnew);           // all-masked first tile self-heals: next alpha==0
            float rs = wave_reduce_sum(p);
            float alpha = expf(m_r[jj] - mnew);
            m_r[jj] = mnew;
            l_r[jj] = l_r[jj] * alpha + rs;

            float pv = 0.0f;
            #pragma unroll
            for (int c = 0; c < 64; c++) {
                float pc = __shfl(p, c, 64);
                pv += pc * vs[c][tx];
            }
            acc[jj] = acc[jj] * alpha + pv;
        }
    }

    #pragma unroll
    for (int jj = 0; jj < 16; jj++) {
        const int r = 4 * jj + ty;
        float v = acc[jj] / l_r[jj];
        size_t idx = (size_t)(qbase + r) * D + h * DH + tx;
        u16 hv = f2bf(v);
        o_hi[idx] = hv;
        o_lo[idx] = f2bf(v - bf2f(hv));
    }
}

// ---------------------------------------------------------------- launch
extern "C" void kernel_launch(void* const* d_in, const int* in_sizes, int n_in,
                              void* d_out, int out_size, void* d_ws, size_t ws_size,
                              hipStream_t stream)
{
    const float* x_in    = (const float*)d_in[0];
    const float* cond    = (const float*)d_in[1];
    const float* qkv_w   = (const float*)d_in[2];
    const float* qkv_b   = (const float*)d_in[3];
    const float* out_w   = (const float*)d_in[4];
    const float* out_b   = (const float*)d_in[5];
    const float* mlp_w1  = (const float*)d_in[6];
    const float* mlp_b1  = (const float*)d_in[7];
    const float* mlp_w2  = (const float*)d_in[8];
    const float* mlp_b2  = (const float*)d_in[9];
    const float* ada1_w  = (const float*)d_in[10];
    const float* ada1_b  = (const float*)d_in[11];
    const float* gate1_w = (const float*)d_in[12];
    const float* gate1_b = (const float*)d_in[13];
    const float* ada2_w  = (const float*)d_in[14];
    const float* ada2_b  = (const float*)d_in[15];
    const float* gate2_w = (const float*)d_in[16];
    const float* gate2_b = (const float*)d_in[17];

    float* x = (float*)d_out;                 // running residual stream

    char* w = (char*)d_ws;
    float* qkv   = (float*)w;  w += (size_t)S * 3 * D * 4;   // 12 MB fp32
    float* mods  = (float*)w;  w += (size_t)L * 6 * D * 4;
    u16* h_hi    = (u16*)w;    w += (size_t)S * D * 2;
    u16* h_lo    = (u16*)w;    w += (size_t)S * D * 2;
    u16* o_hi    = (u16*)w;    w += (size_t)S * D * 2;
    u16* o_lo    = (u16*)w;    w += (size_t)S * D * 2;
    u16* t_hi    = (u16*)w;    w += (size_t)S * DFF * 2;
    u16* t_lo    = (u16*)w;    w += (size_t)S * DFF * 2;
    u16* wb_h    = (u16*)w;    w += (size_t)D * DFF * 2;     // max K*N
    u16* wb_l    = (u16*)w;    w += (size_t)D * DFF * 2;

    hipMemcpyAsync(x, x_in, (size_t)S * D * sizeof(float), hipMemcpyDeviceToDevice, stream);

    modulation_kernel<<<(L * 6 * D) / 256, 256, 0, stream>>>(
        cond, ada1_w, ada1_b, gate1_w, gate1_b, ada2_w, ada2_b, gate2_w, gate2_b, mods);

    for (int l = 0; l < L; l++) {
        const int window = (l % 4 == 0) ? 128 : 8;
        const float* m1 = mods + (size_t)l * 6 * D;

        // ---- attention half
        ln_mod_kernel<<<S, 256, 0, stream>>>(x, m1, h_hi, h_lo);
        convert_w_kernel<<<dim3(3 * D / 64, D / 64), 256, 0, stream>>>(
            qkv_w + (size_t)l * D * 3 * D, wb_h, wb_l, D, 3 * D);
        mfma_gemm<128, 128, 0><<<dim3(3 * D / 128, S / 128), 256, 0, stream>>>(
            h_hi, h_lo, wb_h, wb_l, qkv_b + (size_t)l * 3 * D,
            qkv, nullptr, nullptr, nullptr, nullptr, D, 3 * D);
        qk_prep_kernel<<<S * H, 64, 0, stream>>>(qkv);
        attn_kernel<<<dim3(H, S / 64), 256, 0, stream>>>(qkv, o_hi, o_lo, window);
        convert_w_kernel<<<dim3(D / 64, D / 64), 256, 0, stream>>>(
            out_w + (size_t)l * D * D, wb_h, wb_l, D, D);
        mfma_gemm<64, 128, 2><<<dim3(D / 128, S / 64), 256, 0, stream>>>(
            o_hi, o_lo, wb_h, wb_l, out_b + (size_t)l * D,
            nullptr, nullptr, nullptr, m1 + 2 * D, x, D, D);

        // ---- MLP half
        ln_mod_kernel<<<S, 256, 0, stream>>>(x, m1 + 3 * D, h_hi, h_lo);
        convert_w_kernel<<<dim3(DFF / 64, D / 64), 256, 0, stream>>>(
            mlp_w1 + (size_t)l * D * DFF, wb_h, wb_l, D, DFF);
        mfma_gemm<128, 128, 1><<<dim3(DFF / 128, S / 128), 256, 0, stream>>>(
            h_hi, h_lo, wb_h, wb_l, mlp_b1 + (size_t)l * DFF,
            nullptr, t_hi, t_lo, nullptr, nullptr, D, DFF);
        convert_w_kernel<<<dim3(D / 64, DFF / 64), 256, 0, stream>>>(
            mlp_w2 + (size_t)l * DFF * D, wb_h, wb_l, DFF, D);
        mfma_gemm<64, 128, 2><<<dim3(D / 128, S / 64), 256, 0, stream>>>(
            t_hi, t_lo, wb_h, wb_l, mlp_b2 + (size_t)l * D,
            nullptr, nullptr, nullptr, m1 + 5 * D, x, DFF, D);
    }
}

// Round 5
// 1424.374 us; speedup vs baseline: 1.6605x; 1.6605x over previous
//
#include <hip/hip_runtime.h>
#include <hip/hip_bf16.h>
#include <math.h>

#define S 1024
#define D 1024
#define H 16
#define DH 64
#define L 4
#define DFF 4096

typedef unsigned short u16;
typedef __attribute__((ext_vector_type(8))) short short8;
typedef __attribute__((ext_vector_type(4))) float floatx4;
typedef __attribute__((ext_vector_type(4))) u16 ushort4v;
typedef __attribute__((ext_vector_type(8))) u16 ushort8v;

// async global->LDS, 16B per lane (m97 pattern; size must be literal)
#define GLL16(gp, lp) __builtin_amdgcn_global_load_lds( \
    (const __attribute__((address_space(1))) void*)(gp), \
    (__attribute__((address_space(3))) void*)(lp), 16, 0, 0)

// ---------------------------------------------------------------- helpers
__device__ __forceinline__ float wave_reduce_sum(float v) {
    #pragma unroll
    for (int off = 1; off < 64; off <<= 1) v += __shfl_xor(v, off, 64);
    return v;
}
__device__ __forceinline__ float gelu_f(float x) {
    float x3 = x * x * x;
    return 0.5f * x * (1.0f + tanhf(0.7978845608028654f * (x + 0.044715f * x3)));
}
// bf16 round-to-nearest-even, raw bits
__device__ __forceinline__ u16 f2bf(float x) {
    unsigned u = __float_as_uint(x);
    return (u16)((u + 0x7FFFu + ((u >> 16) & 1u)) >> 16);
}
__device__ __forceinline__ float bf2f(u16 h) {
    return __uint_as_float(((unsigned)h) << 16);
}

// ---------------------------------------------------------------- modulation GEMVs
// mods per layer l (offset l*6*D): [0,2D) shift1|scale1 ; [2D,3D) gate1 ;
// [3D,5D) shift2|scale2 ; [5D,6D) gate2
__global__ __launch_bounds__(256) void modulation_kernel(
    const float* __restrict__ cond,
    const float* __restrict__ ada1_w, const float* __restrict__ ada1_b,
    const float* __restrict__ gate1_w, const float* __restrict__ gate1_b,
    const float* __restrict__ ada2_w, const float* __restrict__ ada2_b,
    const float* __restrict__ gate2_w, const float* __restrict__ gate2_b,
    float* __restrict__ mods)
{
    int idx = blockIdx.x * 256 + threadIdx.x;   // < L*6*D
    int l = idx / (6 * D);
    int r = idx - l * (6 * D);
    const float* w; const float* b; int col, outdim;
    if (r < 2 * D)      { w = ada1_w  + (size_t)l * D * 2 * D; b = ada1_b  + l * 2 * D; col = r;          outdim = 2 * D; }
    else if (r < 3 * D) { w = gate1_w + (size_t)l * D * D;     b = gate1_b + l * D;     col = r - 2 * D;  outdim = D; }
    else if (r < 5 * D) { w = ada2_w  + (size_t)l * D * 2 * D; b = ada2_b  + l * 2 * D; col = r - 3 * D;  outdim = 2 * D; }
    else                { w = gate2_w + (size_t)l * D * D;     b = gate2_b + l * D;     col = r - 5 * D;  outdim = D; }
    float acc = b[col];
    for (int k = 0; k < D; k++) acc += cond[k] * w[(size_t)k * outdim + col];
    mods[idx] = acc;
}

// ---------------------------------------------------------------- LayerNorm + adaLN -> bf16 hi/lo planes
__global__ __launch_bounds__(256) void ln_mod_kernel(
    const float* __restrict__ x, const float* __restrict__ ss,
    u16* __restrict__ out_hi, u16* __restrict__ out_lo)
{
    __shared__ float red[4];
    const int row = blockIdx.x, t = threadIdx.x;
    float4 v = ((const float4*)(x + (size_t)row * D))[t];

    float s = v.x + v.y + v.z + v.w;
    s = wave_reduce_sum(s);
    if ((t & 63) == 0) red[t >> 6] = s;
    __syncthreads();
    float mean = (red[0] + red[1] + red[2] + red[3]) * (1.0f / D);

    float dx = v.x - mean, dy = v.y - mean, dz = v.z - mean, dw = v.w - mean;
    float s2 = dx * dx + dy * dy + dz * dz + dw * dw;
    __syncthreads();
    s2 = wave_reduce_sum(s2);
    if ((t & 63) == 0) red[t >> 6] = s2;
    __syncthreads();
    float var = (red[0] + red[1] + red[2] + red[3]) * (1.0f / D);
    float rstd = rsqrtf(var + 1e-5f);

    int c = t * 4;
    float ov[4];
    ov[0] = dx * rstd * (1.0f + ss[D + c + 0]) + ss[c + 0];
    ov[1] = dy * rstd * (1.0f + ss[D + c + 1]) + ss[c + 1];
    ov[2] = dz * rstd * (1.0f + ss[D + c + 2]) + ss[c + 2];
    ov[3] = dw * rstd * (1.0f + ss[D + c + 3]) + ss[c + 3];
    ushort4v hv, lv;
    #pragma unroll
    for (int j = 0; j < 4; j++) {
        u16 h = f2bf(ov[j]);
        hv[j] = h;
        lv[j] = f2bf(ov[j] - bf2f(h));
    }
    *(ushort4v*)&out_hi[(size_t)row * D + c] = hv;
    *(ushort4v*)&out_lo[(size_t)row * D + c] = lv;
}

// ---------------------------------------------------------------- weight convert+transpose: W[K][N] f32 -> Wt hi/lo [N][K] bf16
__global__ __launch_bounds__(256) void convert_w_kernel(
    const float* __restrict__ W, u16* __restrict__ Wh, u16* __restrict__ Wl,
    int K, int N)
{
    __shared__ float t[64][65];
    const int n0 = blockIdx.x * 64, k0 = blockIdx.y * 64;
    const int tid = threadIdx.x;
    const int r = tid >> 4, c4 = (tid & 15) * 4;
    #pragma unroll
    for (int i = 0; i < 4; i++) {
        float4 v = *(const float4*)(W + (size_t)(k0 + r + i * 16) * N + n0 + c4);
        t[r + i * 16][c4 + 0] = v.x;
        t[r + i * 16][c4 + 1] = v.y;
        t[r + i * 16][c4 + 2] = v.z;
        t[r + i * 16][c4 + 3] = v.w;
    }
    __syncthreads();
    const int n = tid >> 2, kc = (tid & 3) * 16;
    ushort8v h0, h1, l0, l1;
    #pragma unroll
    for (int j = 0; j < 8; j++) {
        float x0 = t[kc + j][n];
        float x1 = t[kc + 8 + j][n];
        u16 a = f2bf(x0), b = f2bf(x1);
        h0[j] = a; h1[j] = b;
        l0[j] = f2bf(x0 - bf2f(a));
        l1[j] = f2bf(x1 - bf2f(b));
    }
    size_t base = (size_t)(n0 + n) * K + k0 + kc;
    *(ushort8v*)&Wh[base]     = h0;
    *(ushort8v*)&Wh[base + 8] = h1;
    *(ushort8v*)&Wl[base]     = l0;
    *(ushort8v*)&Wl[base + 8] = l1;
}

// ---------------------------------------------------------------- bf16x3 MFMA GEMM
// C[M,N] = epi(A[M,K] @ B^T, + bias); A,B as bf16 hi/lo planes; B pre-transposed [N][K].
// MODE 0: C fp32      MODE 1: gelu -> Ch/Cl bf16 planes     MODE 2: X += r*gate (fp32 RMW)
template<int BM, int BN, int MODE>
__global__ __launch_bounds__(256, 2) void mfma_gemm(
    const u16* __restrict__ Ah, const u16* __restrict__ Al,
    const u16* __restrict__ Bh, const u16* __restrict__ Bl,
    const float* __restrict__ bias,
    float* __restrict__ C, u16* __restrict__ Ch, u16* __restrict__ Cl,
    const float* __restrict__ gate, float* __restrict__ X,
    int K, int N)
{
    constexpr int SAe = BM * 32;            // elems per A plane (BK=32)
    constexpr int SBe = BN * 32;
    constexpr int SBUFE = 2 * SAe + 2 * SBe;
    constexpr int NSWEEP = SBUFE / 2048;    // 256 thr * 8 elems each
    constexpr int WM = BM / 2, WN = BN / 2; // 2x2 waves
    constexpr int FM = WM / 16, FN = WN / 16;

    __shared__ u16 shm[2 * SBUFE];

    const int tid  = threadIdx.x;
    const int lane = tid & 63;
    const int wave = tid >> 6;
    const int wm = wave >> 1, wn = wave & 1;

    // T1: XCD-aware bijective swizzle (all grids here have nwg % 8 == 0)
    const int nwg = gridDim.x * gridDim.y;
    int bid = blockIdx.y * gridDim.x + blockIdx.x;
    bid = (bid & 7) * (nwg >> 3) + (bid >> 3);
    const int bm = (bid / gridDim.x) * BM;
    const int bn = (bid % gridDim.x) * BN;

    const u16* gA0 = Ah + (size_t)bm * K;
    const u16* gA1 = Al + (size_t)bm * K;
    const u16* gB0 = Bh + (size_t)bn * K;
    const u16* gB1 = Bl + (size_t)bn * K;

    // LDS[phys] = G[inv(phys)]; reader uses fwd swz. fwd: e^=(e&0xE0)>>2
    // inverse: e^=((e&0xE0)>>2)^((e&0x80)>>4)   (verified involution-pair)
    auto stage = [&](int bufe, int kt) {
        const int k0 = kt * 32;
        #pragma unroll
        for (int s = 0; s < NSWEEP; s++) {
            const int pbase = s * 2048;
            const int oe = pbase + tid * 8;
            const u16* src; int pe;
            if (pbase < SAe)               { src = gA0; pe = oe; }
            else if (pbase < 2 * SAe)      { src = gA1; pe = oe - SAe; }
            else if (pbase < 2 * SAe + SBe){ src = gB0; pe = oe - 2 * SAe; }
            else                           { src = gB1; pe = oe - 2 * SAe - SBe; }
            const int ue = pe ^ ((pe & 0xE0) >> 2) ^ ((pe & 0x80) >> 4);
            const u16* g = src + (size_t)(ue >> 5) * K + k0 + (ue & 31);
            GLL16(g, &shm[bufe + oe]);
        }
    };

    floatx4 acc[FM][FN] = {};

    const int KT = K >> 5;
    stage(0, 0);
    __syncthreads();
    for (int kt = 0; kt < KT; kt++) {
        const int cur = (kt & 1) ? SBUFE : 0;
        if (kt + 1 < KT) stage(cur ^ SBUFE, kt + 1);

        short8 bhf[FN], blf[FN];
        #pragma unroll
        for (int ni = 0; ni < FN; ni++) {
            int row = wn * WN + ni * 16 + (lane & 15);
            int off = row * 32 + ((lane >> 4) << 3);
            off ^= (off & 0xE0) >> 2;
            bhf[ni] = *(const short8*)&shm[cur + 2 * SAe + off];
            blf[ni] = *(const short8*)&shm[cur + 2 * SAe + SBe + off];
        }
        #pragma unroll
        for (int mi = 0; mi < FM; mi++) {
            int row = wm * WM + mi * 16 + (lane & 15);
            int off = row * 32 + ((lane >> 4) << 3);
            off ^= (off & 0xE0) >> 2;
            short8 ahf = *(const short8*)&shm[cur + off];
            short8 alf = *(const short8*)&shm[cur + SAe + off];
            #pragma unroll
            for (int ni = 0; ni < FN; ni++) {
                acc[mi][ni] = __builtin_amdgcn_mfma_f32_16x16x32_bf16(ahf, bhf[ni], acc[mi][ni], 0, 0, 0);
                acc[mi][ni] = __builtin_amdgcn_mfma_f32_16x16x32_bf16(ahf, blf[ni], acc[mi][ni], 0, 0, 0);
                acc[mi][ni] = __builtin_amdgcn_mfma_f32_16x16x32_bf16(alf, bhf[ni], acc[mi][ni], 0, 0, 0);
            }
        }
        __syncthreads();
    }

    // epilogue: C/D frag col=lane&15, row=(lane>>4)*4+reg (m89/m91-verified)
    const int cr = (lane >> 4) << 2;
    const int cc = lane & 15;
    #pragma unroll
    for (int mi = 0; mi < FM; mi++) {
        #pragma unroll
        for (int ni = 0; ni < FN; ni++) {
            const int gcol = bn + wn * WN + ni * 16 + cc;
            const float bv = bias[gcol];
            #pragma unroll
            for (int r = 0; r < 4; r++) {
                const int grow = bm + wm * WM + mi * 16 + cr + r;
                float v = acc[mi][ni][r] + bv;
                if (MODE == 0) {
                    C[(size_t)grow * N + gcol] = v;
                } else if (MODE == 1) {
                    v = gelu_f(v);
                    u16 h = f2bf(v);
                    Ch[(size_t)grow * N + gcol] = h;
                    Cl[(size_t)grow * N + gcol] = f2bf(v - bf2f(h));
                } else {
                    X[(size_t)grow * N + gcol] += v * gate[gcol];
                }
            }
        }
    }
}

// ---------------------------------------------------------------- q/k RMSNorm + RoPE + bf16 pack
// Writes Qb[H][S][64], Kb[H][S][64], Vt[H][64][S] (bf16). qkv fp32 untouched.
__global__ __launch_bounds__(64) void qk_prep_kernel(
    const float* __restrict__ qkv,
    u16* __restrict__ Qb, u16* __restrict__ Kb, u16* __restrict__ Vt)
{
    const int s = blockIdx.x >> 4;
    const int h = blockIdx.x & 15;
    const int d = threadIdx.x;

    const int j = d & 31;
    float ang = (float)s * powf(10000.0f, -(float)j / 32.0f);
    float sn, cs;
    sincosf(ang, &sn, &cs);

    // q
    {
        const float* p = qkv + (size_t)s * (3 * D) + h * DH;
        float v = p[d];
        float rms = rsqrtf(wave_reduce_sum(v * v) * (1.0f / DH) + 1e-6f);
        float vn = v * rms;
        float other = __shfl_xor(vn, 32, 64);
        float out = (d < 32) ? (vn * cs - other * sn) : (other * sn + vn * cs);
        Qb[((size_t)h * S + s) * DH + d] = f2bf(out);
    }
    // k
    {
        const float* p = qkv + (size_t)s * (3 * D) + D + h * DH;
        float v = p[d];
        float rms = rsqrtf(wave_reduce_sum(v * v) * (1.0f / DH) + 1e-6f);
        float vn = v * rms;
        float other = __shfl_xor(vn, 32, 64);
        float out = (d < 32) ? (vn * cs - other * sn) : (other * sn + vn * cs);
        Kb[((size_t)h * S + s) * DH + d] = f2bf(out);
    }
    // v (transpose scatter)
    {
        float v = qkv[(size_t)s * (3 * D) + 2 * D + h * DH + d];
        Vt[((size_t)h * DH + d) * S + s] = f2bf(v);
    }
}

// ---------------------------------------------------------------- MFMA flash attention
// block = (head, 64-row q-tile), 4 waves x 16-row strips. bf16 QK^T / PV, fp32 softmax.
// LDS swizzle: u16 idx ^= (row&7)<<3  (byte ^= (row&7)<<4, G4 pattern)
__global__ __launch_bounds__(256) void attn_mfma_kernel(
    const u16* __restrict__ Qb, const u16* __restrict__ Kb, const u16* __restrict__ Vt,
    u16* __restrict__ o_hi, u16* __restrict__ o_lo, int window)
{
    __shared__ u16 Qs[64 * 64];
    __shared__ u16 Ks[64 * 64];
    __shared__ u16 Vs[64 * 64];   // V^T tile: [d][kk]
    __shared__ u16 Ps[64 * 64];   // [qrow][kk]

    const int h   = blockIdx.x;
    const int qt  = blockIdx.y;
    const int tid = threadIdx.x;
    const int lane = tid & 63;
    const int w    = tid >> 6;
    const int qbase = qt * 64;

    const int srow0 = tid >> 3;         // staging row 0..31 (+32 on second pass)
    const int sc0   = (tid & 7) * 8;    // staging col 0..56

    // stage Q once (2 rows/thread: 256 thr x 8 elems x 2 = 4096)
    #pragma unroll
    for (int rr = 0; rr < 2; rr++) {
        const int row = srow0 + rr * 32;
        ushort8v v = *(const ushort8v*)&Qb[((size_t)h * S + qbase + row) * DH + sc0];
        *(ushort8v*)&Qs[(row * 64 + sc0) ^ ((row & 7) << 3)] = v;
    }
    __syncthreads();

    // hoist Q frags (strip = w*16 rows)
    short8 qf[2];
    {
        int row = w * 16 + (lane & 15);
        #pragma unroll
        for (int ks = 0; ks < 2; ks++)
            qf[ks] = *(const short8*)&Qs[(row * 64 + ks * 32 + ((lane >> 4) << 3)) ^ ((row & 7) << 3)];
    }

    floatx4 acc[4] = {};                 // [nd] ; reg r = row within lane's 4 rows
    float m_r[4] = { -INFINITY, -INFINITY, -INFINITY, -INFINITY };
    float l_r[4] = {};

    int kt0 = qbase - (window - 1) * 8;
    kt0 = (kt0 < 0) ? 0 : (kt0 >> 6);

    for (int kt = kt0; kt <= qt; kt++) {
        const int kbase = kt * 64;
        if (kt > kt0) __syncthreads();   // protect Ks/Vs overwrite vs previous iteration's reads
        #pragma unroll
        for (int rr = 0; rr < 2; rr++) {
            const int row = srow0 + rr * 32;
            ushort8v kv = *(const ushort8v*)&Kb[((size_t)h * S + kbase + row) * DH + sc0];
            *(ushort8v*)&Ks[(row * 64 + sc0) ^ ((row & 7) << 3)] = kv;
            ushort8v vv = *(const ushort8v*)&Vt[((size_t)h * DH + row) * S + kbase + sc0];
            *(ushort8v*)&Vs[(row * 64 + sc0) ^ ((row & 7) << 3)] = vv;
        }
        __syncthreads();

        // QK^T: sc[ni] = Q-strip (16xK) x K-tile cols (ni*16..)
        floatx4 sc[4] = {};
        #pragma unroll
        for (int ni = 0; ni < 4; ni++) {
            int kr = ni * 16 + (lane & 15);
            #pragma unroll
            for (int ks = 0; ks < 2; ks++) {
                short8 kf = *(const short8*)&Ks[(kr * 64 + ks * 32 + ((lane >> 4) << 3)) ^ ((kr & 7) << 3)];
                sc[ni] = __builtin_amdgcn_mfma_f32_16x16x32_bf16(qf[ks], kf, sc[ni], 0, 0, 0);
            }
        }

        // mask + scale (C-frag: col=lane&15, row=(lane>>4)*4+r)
        float val[4][4];
        #pragma unroll
        for (int ni = 0; ni < 4; ni++) {
            const int fk = (kbase + ni * 16 + (lane & 15)) >> 3;
            #pragma unroll
            for (int r = 0; r < 4; r++) {
                const int fq = (qbase + w * 16 + ((lane >> 4) << 2) + r) >> 3;
                bool ok = (fk <= fq) && ((fq - fk) < window);
                val[ni][r] = ok ? sc[ni][r] * 0.125f : -1e30f;
            }
        }

        // online softmax per row r (row group = 16 lanes sharing lane>>4)
        #pragma unroll
        for (int r = 0; r < 4; r++) {
            float mt = fmaxf(fmaxf(val[0][r], val[1][r]), fmaxf(val[2][r], val[3][r]));
            #pragma unroll
            for (int off = 1; off < 16; off <<= 1) mt = fmaxf(mt, __shfl_xor(mt, off, 64));
            float mnew = fmaxf(m_r[r], mt);
            float alpha = expf(m_r[r] - mnew);   // -inf - finite -> 0 ; all-masked-first-tile self-heals
            float rs = 0.0f;
            #pragma unroll
            for (int ni = 0; ni < 4; ni++) {
                float p = expf(val[ni][r] - mnew);
                val[ni][r] = p;
                rs += p;
            }
            #pragma unroll
            for (int off = 1; off < 16; off <<= 1) rs += __shfl_xor(rs, off, 64);
            m_r[r] = mnew;
            l_r[r] = l_r[r] * alpha + rs;
            #pragma unroll
            for (int nd = 0; nd < 4; nd++) acc[nd][r] *= alpha;
        }

        // P -> LDS bf16 (each wave writes only its own 16-row strip)
        #pragma unroll
        for (int ni = 0; ni < 4; ni++) {
            #pragma unroll
            for (int r = 0; r < 4; r++) {
                int prow = w * 16 + ((lane >> 4) << 2) + r;
                Ps[(prow * 64 + ni * 16 + (lane & 15)) ^ ((prow & 7) << 3)] = f2bf(val[ni][r]);
            }
        }
        __syncthreads();

        // PV: acc[nd] += P-strip x V^T cols
        {
            int prow = w * 16 + (lane & 15);
            #pragma unroll
            for (int ks = 0; ks < 2; ks++) {
                short8 pf = *(const short8*)&Ps[(prow * 64 + ks * 32 + ((lane >> 4) << 3)) ^ ((prow & 7) << 3)];
                #pragma unroll
                for (int nd = 0; nd < 4; nd++) {
                    int vr = nd * 16 + (lane & 15);
                    short8 vf = *(const short8*)&Vs[(vr * 64 + ks * 32 + ((lane >> 4) << 3)) ^ ((vr & 7) << 3)];
                    acc[nd] = __builtin_amdgcn_mfma_f32_16x16x32_bf16(pf, vf, acc[nd], 0, 0, 0);
                }
            }
        }
    }

    // epilogue: o[qrow][h*64+d] hi/lo
    #pragma unroll
    for (int nd = 0; nd < 4; nd++) {
        const int d = nd * 16 + (lane & 15);
        #pragma unroll
        for (int r = 0; r < 4; r++) {
            const int grow = qbase + w * 16 + ((lane >> 4) << 2) + r;
            float v = acc[nd][r] / l_r[r];
            size_t idx = (size_t)grow * D + h * DH + d;
            u16 hv = f2bf(v);
            o_hi[idx] = hv;
            o_lo[idx] = f2bf(v - bf2f(hv));
        }
    }
}

// ---------------------------------------------------------------- launch
extern "C" void kernel_launch(void* const* d_in, const int* in_sizes, int n_in,
                              void* d_out, int out_size, void* d_ws, size_t ws_size,
                              hipStream_t stream)
{
    const float* x_in    = (const float*)d_in[0];
    const float* cond    = (const float*)d_in[1];
    const float* qkv_w   = (const float*)d_in[2];
    const float* qkv_b   = (const float*)d_in[3];
    const float* out_w   = (const float*)d_in[4];
    const float* out_b   = (const float*)d_in[5];
    const float* mlp_w1  = (const float*)d_in[6];
    const float* mlp_b1  = (const float*)d_in[7];
    const float* mlp_w2  = (const float*)d_in[8];
    const float* mlp_b2  = (const float*)d_in[9];
    const float* ada1_w  = (const float*)d_in[10];
    const float* ada1_b  = (const float*)d_in[11];
    const float* gate1_w = (const float*)d_in[12];
    const float* gate1_b = (const float*)d_in[13];
    const float* ada2_w  = (const float*)d_in[14];
    const float* ada2_b  = (const float*)d_in[15];
    const float* gate2_w = (const float*)d_in[16];
    const float* gate2_b = (const float*)d_in[17];

    float* x = (float*)d_out;                 // running residual stream

    char* w = (char*)d_ws;
    float* qkv   = (float*)w;  w += (size_t)S * 3 * D * 4;   // 12 MB fp32
    float* mods  = (float*)w;  w += (size_t)L * 6 * D * 4;
    u16* h_hi    = (u16*)w;    w += (size_t)S * D * 2;
    u16* h_lo    = (u16*)w;    w += (size_t)S * D * 2;
    u16* o_hi    = (u16*)w;    w += (size_t)S * D * 2;
    u16* o_lo    = (u16*)w;    w += (size_t)S * D * 2;
    u16* t_hi    = (u16*)w;    w += (size_t)S * DFF * 2;
    u16* t_lo    = (u16*)w;    w += (size_t)S * DFF * 2;
    u16* wb_h    = (u16*)w;    w += (size_t)D * DFF * 2;     // max K*N
    u16* wb_l    = (u16*)w;    w += (size_t)D * DFF * 2;
    u16* Qb      = (u16*)w;    w += (size_t)S * D * 2;       // [H][S][64]
    u16* Kb      = (u16*)w;    w += (size_t)S * D * 2;       // [H][S][64]
    u16* Vt      = (u16*)w;    w += (size_t)S * D * 2;       // [H][64][S]

    hipMemcpyAsync(x, x_in, (size_t)S * D * sizeof(float), hipMemcpyDeviceToDevice, stream);

    modulation_kernel<<<(L * 6 * D) / 256, 256, 0, stream>>>(
        cond, ada1_w, ada1_b, gate1_w, gate1_b, ada2_w, ada2_b, gate2_w, gate2_b, mods);

    for (int l = 0; l < L; l++) {
        const int window = (l % 4 == 0) ? 128 : 8;
        const float* m1 = mods + (size_t)l * 6 * D;

        // ---- attention half
        ln_mod_kernel<<<S, 256, 0, stream>>>(x, m1, h_hi, h_lo);
        convert_w_kernel<<<dim3(3 * D / 64, D / 64), 256, 0, stream>>>(
            qkv_w + (size_t)l * D * 3 * D, wb_h, wb_l, D, 3 * D);
        mfma_gemm<128, 128, 0><<<dim3(3 * D / 128, S / 128), 256, 0, stream>>>(
            h_hi, h_lo, wb_h, wb_l, qkv_b + (size_t)l * 3 * D,
            qkv, nullptr, nullptr, nullptr, nullptr, D, 3 * D);
        qk_prep_kernel<<<S * H, 64, 0, stream>>>(qkv, Qb, Kb, Vt);
        attn_mfma_kernel<<<dim3(H, S / 64), 256, 0, stream>>>(Qb, Kb, Vt, o_hi, o_lo, window);
        convert_w_kernel<<<dim3(D / 64, D / 64), 256, 0, stream>>>(
            out_w + (size_t)l * D * D, wb_h, wb_l, D, D);
        mfma_gemm<64, 128, 2><<<dim3(D / 128, S / 64), 256, 0, stream>>>(
            o_hi, o_lo, wb_h, wb_l, out_b + (size_t)l * D,
            nullptr, nullptr, nullptr, m1 + 2 * D, x, D, D);

        // ---- MLP half
        ln_mod_kernel<<<S, 256, 0, stream>>>(x, m1 + 3 * D, h_hi, h_lo);
        convert_w_kernel<<<dim3(DFF / 64, D / 64), 256, 0, stream>>>(
            mlp_w1 + (size_t)l * D * DFF, wb_h, wb_l, D, DFF);
        mfma_gemm<128, 128, 1><<<dim3(DFF / 128, S / 128), 256, 0, stream>>>(
            h_hi, h_lo, wb_h, wb_l, mlp_b1 + (size_t)l * DFF,
            nullptr, t_hi, t_lo, nullptr, nullptr, D, DFF);
        convert_w_kernel<<<dim3(D / 64, DFF / 64), 256, 0, stream>>>(
            mlp_w2 + (size_t)l * DFF * D, wb_h, wb_l, DFF, D);
        mfma_gemm<64, 128, 2><<<dim3(D / 128, S / 64), 256, 0, stream>>>(
            t_hi, t_lo, wb_h, wb_l, mlp_b2 + (size_t)l * D,
            nullptr, nullptr, nullptr, m1 + 5 * D, x, DFF, D);
    }
}